// Round 9
// baseline (159.200 us; speedup 1.0000x reference)
//
#include <hip/hip_runtime.h>

// Problem constants (from reference): x (2,14,128,256,96) f32, wid (2,128,256) int
namespace {
constexpr int kB   = 2;
constexpr int kPl  = 14;
constexpr int kLat = 128;
constexpr int kLon = 256;
constexpr int kC   = 96;
constexpr int kNumDirs = 9;
constexpr int kC4  = kC / 4;                         // 24 float4 per row
constexpr int kNTotal = kB * kPl * kLat * kLon * kC; // 88,080,384
constexpr int kRowTasks = kB * kPl * kLat;           // 3584 (one output lat-row each)
constexpr int kRowF4 = kLon * kC4;                   // 6144 f4 = 96 KB per row
constexpr int kRowIters = kRowF4 / 256;              // 24 per thread
constexpr int kWidTotal = kB * kLat * kLon;          // 65536
}

typedef float f4 __attribute__((ext_vector_type(4)));

// WIND_DIRS lat/lon shifts: dir -> (lat_s, lon_s)
// 0:(0,0) 1:(-1,0) 2:(-1,1) 3:(0,1) 4:(1,1) 5:(1,0) 6:(1,-1) 7:(0,-1) 8:(-1,-1)
__device__ __constant__ int c_lat_s[kNumDirs] = {0,-1,-1, 0, 1, 1, 1, 0,-1};
__device__ __constant__ int c_lon_s[kNumDirs] = {0, 0, 1, 1, 1, 0,-1,-1,-1};

// Single fused kernel.
// Blocks 0..kRowTasks-1: copy one output lat-row (b,p,la).
//   Prologue: compute this row's 8 region-dominant packs from wid via
//   wave-uniform ballot histograms (no atomics; wid is L2/L3-resident).
//   Body: 96 KB sequential nt-store write, 8 contiguous ~12 KB read segments,
//   plain loads (retain x in L3 across replays).
// Block kRowTasks: full-wid ballot histogram -> global dominant id.
__global__ __launch_bounds__(256) void fused_gather_kernel(
        const f4* __restrict__ x, const int* __restrict__ wid,
        f4* __restrict__ out, float* __restrict__ out_dom) {
    const int t    = threadIdx.x;
    const int wave = t >> 6;
    const int lane = t & 63;

    if (blockIdx.x == kRowTasks) {
        // ---- global dominant direction over all 65536 wid values ----
        __shared__ int s_gcnt[4][kNumDirs];
        int cnt[kNumDirs];
        #pragma unroll
        for (int d = 0; d < kNumDirs; ++d) cnt[d] = 0;
        const int* w = wid + wave * (kWidTotal / 4);
        for (int k = 0; k < kWidTotal / 4 / 64; ++k) {          // 256 iters
            const int v = w[k * 64 + lane];
            #pragma unroll
            for (int d = 0; d < kNumDirs; ++d)
                cnt[d] += (int)__popcll(__ballot(v == d));
        }
        if (lane == 0) {
            #pragma unroll
            for (int d = 0; d < kNumDirs; ++d) s_gcnt[wave][d] = cnt[d];
        }
        __syncthreads();
        if (t == 0) {
            int best = 0, bestc = -1;
            #pragma unroll
            for (int d = 0; d < kNumDirs; ++d) {
                const int s = s_gcnt[0][d] + s_gcnt[1][d] + s_gcnt[2][d] + s_gcnt[3][d];
                if (s > bestc) { bestc = s; best = d; }          // first-max tie
            }
            *out_dom = (float)best;
        }
        return;
    }

    // ---- copy block: identify row ----
    const int blk = blockIdx.x;            // task = (b*kPl + p)*kLat + la
    const int la  = blk & (kLat - 1);
    const int bp  = blk >> 7;
    const int p   = bp % kPl;
    const int b   = bp / kPl;
    int psrc = p + 1; if (psrc >= kPl) psrc = 0;
    const int laR = la >> 5;

    // ---- prologue: 8 region packs via ballot histograms ----
    __shared__ int s_cnt[8][kNumDirs];
    __shared__ int s_pack8[8];
    {
        const int* wbase = wid + (b * kLat + laR * 32) * kLon;   // 32 lat rows
        #pragma unroll
        for (int rr = 0; rr < 2; ++rr) {
            const int r = wave * 2 + rr;                         // region 0..7
            int cnt[kNumDirs];
            #pragma unroll
            for (int d = 0; d < kNumDirs; ++d) cnt[d] = 0;
            const int* wreg = wbase + r * 32;                    // lon offset
            #pragma unroll
            for (int k = 0; k < 16; ++k) {                       // 1024 vals/region
                const int idx = k * 64 + lane;                   // 0..1023
                const int v = wreg[(idx >> 5) * kLon + (idx & 31)];
                #pragma unroll
                for (int d = 0; d < kNumDirs; ++d)
                    cnt[d] += (int)__popcll(__ballot(v == d));
            }
            if (lane == 0) {
                #pragma unroll
                for (int d = 0; d < kNumDirs; ++d) s_cnt[r][d] = cnt[d];
            }
        }
    }
    __syncthreads();
    if (t < 8) {
        int best = 0, bestc = s_cnt[t][0];
        #pragma unroll
        for (int d = 1; d < kNumDirs; ++d)
            if (s_cnt[t][d] > bestc) { bestc = s_cnt[t][d]; best = d; }
        const int dla = 3 - 2 * c_lat_s[best];   // {1,3,5}
        const int dlo = 6 - 2 * c_lon_s[best];   // {4,6,8}
        s_pack8[t] = (dla << 8) | dlo;
    }
    __syncthreads();

    // ---- body: row copy (identical to R8 winner) ----
    const long srow = (long)((b * kPl + psrc) * kLat) * kRowF4;  // source plane base
    const long drow = (long)blk * kRowF4;                        // this output row

    #pragma unroll 6
    for (int k = 0; k < kRowIters; ++k) {
        const int flat = k * 256 + t;        // 0..6143, block-sequential
        const int lo   = flat / kC4;
        const int c4   = flat - lo * kC4;

        const int pack  = s_pack8[lo >> 5];
        const int lasrc = (la + (pack >> 8)) & (kLat - 1);
        const int losrc = (lo + (pack & 0xff)) & (kLon - 1);

        const long src = srow + (long)lasrc * kRowF4 + losrc * kC4 + c4;
        const f4 v = x[src];                               // plain load: keep in L3
        __builtin_nontemporal_store(v, &out[drow + flat]); // nt store
    }
}

extern "C" void kernel_launch(void* const* d_in, const int* in_sizes, int n_in,
                              void* d_out, int out_size, void* d_ws, size_t ws_size,
                              hipStream_t stream) {
    const float* x   = (const float*)d_in[0];
    const int*   wid = (const int*)d_in[1];
    float* out = (float*)d_out;

    fused_gather_kernel<<<kRowTasks + 1, 256, 0, stream>>>(
        (const f4*)x, wid, (f4*)out, out + kNTotal);
}

// Round 10
// 130.374 us; speedup vs baseline: 1.2211x; 1.2211x over previous
//
#include <hip/hip_runtime.h>

// Problem constants (from reference): x (2,14,128,256,96) f32, wid (2,128,256) int
namespace {
constexpr int kB   = 2;
constexpr int kPl  = 14;
constexpr int kLat = 128;
constexpr int kLon = 256;
constexpr int kC   = 96;
constexpr int kNumDirs = 9;
constexpr int kC4  = kC / 4;                         // 24 float4 per row
constexpr int kNTotal = kB * kPl * kLat * kLon * kC; // 88,080,384
constexpr int kRegions = kB * 4 * 8;                 // 64
constexpr int kRowTasks = kB * kPl * kLat;           // 3584 (one output lat-row each)
constexpr int kRowF4 = kLon * kC4;                   // 6144 f4 = 96 KB per row
constexpr int kRowIters = kRowF4 / 256;              // 24 per thread
constexpr int kNumXcd = 8;
constexpr int kChunk  = kRowTasks / kNumXcd;         // 448 (exact -> bijective swizzle)
}

typedef float f4 __attribute__((ext_vector_type(4)));

// WIND_DIRS lat/lon shifts (scale 2 applied in packing):
// dir: 0:(0,0) 1:(-1,0) 2:(-1,1) 3:(0,1) 4:(1,1) 5:(1,0) 6:(1,-1) 7:(0,-1) 8:(-1,-1)
__device__ __constant__ int c_lat_s[kNumDirs] = {0,-1,-1, 0, 1, 1, 1, 0,-1};
__device__ __constant__ int c_lon_s[kNumDirs] = {0, 0, 1, 1, 1, 0,-1,-1,-1};

// One block per (b, rlat, rlon) 32x32 region.
__global__ __launch_bounds__(256) void region_dirs_kernel(
        const int* __restrict__ wid, int* __restrict__ rdpack,
        int* __restrict__ cnt_blk) {
    __shared__ int cnt[kNumDirs];
    const int t = threadIdx.x;
    if (t < kNumDirs) cnt[t] = 0;
    __syncthreads();

    const int blk  = blockIdx.x;        // 0..63
    const int rlon = blk & 7;
    const int rlat = (blk >> 3) & 3;
    const int b    = blk >> 5;

    for (int k = t; k < 1024; k += 256) {
        const int i  = k >> 5;
        const int j  = k & 31;
        const int la = rlat * 32 + i;
        const int lo = rlon * 32 + j;
        atomicAdd(&cnt[wid[(b * kLat + la) * kLon + lo]], 1);
    }
    __syncthreads();

    if (t < kNumDirs) cnt_blk[blk * kNumDirs + t] = cnt[t];
    if (t == 0) {
        int best = 0, bestc = cnt[0];
        #pragma unroll
        for (int d = 1; d < kNumDirs; ++d)
            if (cnt[d] > bestc) { bestc = cnt[d]; best = d; }  // first-max tie
        const int dla = 3 - 2 * c_lat_s[best];   // {1,3,5}
        const int dlo = 6 - 2 * c_lon_s[best];   // {4,6,8}
        rdpack[blk] = (dla << 8) | dlo;
    }
}

// One block per output lat-row (b,p,la): 96 KB sequential nt-store write, 8
// contiguous ~12 KB plain-load read segments. XCD-chunked blockIdx swizzle:
// consecutive la-tasks land on the SAME XCD, so the overlapping source rows
// (la+{1,3,5}) are served from that XCD's L2 instead of shared L3.
__global__ __launch_bounds__(256) void gather_rows_kernel(
        const f4* __restrict__ x, const int* __restrict__ rdpack,
        const int* __restrict__ cnt_blk, f4* __restrict__ out,
        float* __restrict__ out_dom) {
    if (blockIdx.x == kRowTasks) {
        // global dominant direction: sum 64 region histograms, first-max argmax
        __shared__ int tot[kNumDirs];
        const int t = threadIdx.x;
        if (t < kNumDirs) {
            int s = 0;
            for (int r = 0; r < kRegions; ++r) s += cnt_blk[r * kNumDirs + t];
            tot[t] = s;
        }
        __syncthreads();
        if (t == 0) {
            int best = 0, bestc = tot[0];
            #pragma unroll
            for (int d = 1; d < kNumDirs; ++d)
                if (tot[d] > bestc) { bestc = tot[d]; best = d; }
            *out_dom = (float)best;
        }
        return;
    }

    // bijective XCD swizzle (kRowTasks % 8 == 0): XCD k owns tasks [k*448, (k+1)*448)
    const int bid = blockIdx.x;
    const int blk = (bid % kNumXcd) * kChunk + bid / kNumXcd;

    const int t  = threadIdx.x;
    const int la = blk & (kLat - 1);       // task = (b*kPl + p)*kLat + la
    const int bp = blk >> 7;
    const int p  = bp % kPl;
    const int b  = bp / kPl;
    int psrc = p + 1; if (psrc >= kPl) psrc = 0;

    // 8-entry pack row for this (b, la-region): block-uniform
    __shared__ int s_pack8[8];
    if (t < 8) s_pack8[t] = rdpack[(b * 4 + (la >> 5)) * 8 + t];
    __syncthreads();

    const long srow = (long)((b * kPl + psrc) * kLat) * kRowF4; // source plane base
    const long drow = (long)blk * kRowF4;                       // this output row

    #pragma unroll 6
    for (int k = 0; k < kRowIters; ++k) {
        const int flat = k * 256 + t;        // 0..6143, block-sequential
        const int lo   = flat / kC4;
        const int c4   = flat - lo * kC4;

        const int pack  = s_pack8[lo >> 5];
        const int lasrc = (la + (pack >> 8)) & (kLat - 1);
        const int losrc = (lo + (pack & 0xff)) & (kLon - 1);

        const long src = srow + (long)lasrc * kRowF4 + losrc * kC4 + c4;
        const f4 v = x[src];                               // plain load: keep in L3
        __builtin_nontemporal_store(v, &out[drow + flat]); // nt store: don't cache out
    }
}

extern "C" void kernel_launch(void* const* d_in, const int* in_sizes, int n_in,
                              void* d_out, int out_size, void* d_ws, size_t ws_size,
                              hipStream_t stream) {
    const float* x   = (const float*)d_in[0];
    const int*   wid = (const int*)d_in[1];
    float* out = (float*)d_out;

    // ws layout: [0..63] rdpack, [64..64+576) per-block counts
    int* rdpack  = (int*)d_ws;
    int* cnt_blk = rdpack + kRegions;

    region_dirs_kernel<<<kRegions, 256, 0, stream>>>(wid, rdpack, cnt_blk);
    gather_rows_kernel<<<kRowTasks + 1, 256, 0, stream>>>(
        (const f4*)x, rdpack, cnt_blk, (f4*)out, out + kNTotal);
}